// Round 1
// baseline (511.476 us; speedup 1.0000x reference)
//
#include <hip/hip_runtime.h>
#include <hip/hip_bf16.h>

#define NUM 8192
#define DIM 256

typedef __bf16 bf16x8 __attribute__((ext_vector_type(8)));
typedef float f32x4 __attribute__((ext_vector_type(4)));

// float -> bf16 round-to-nearest-even
__device__ __forceinline__ unsigned short f2bf(float x) {
  unsigned int u = __float_as_uint(x);
  unsigned int r = (u + 0x7FFFu + ((u >> 16) & 1u)) >> 16;
  return (unsigned short)r;
}

// async global->LDS, 16B per lane. LDS dest must be wave-uniform base + lane*16.
__device__ __forceinline__ void async_copy16(const void* g, void* l) {
  __builtin_amdgcn_global_load_lds(
      (const __attribute__((address_space(1))) void*)g,
      (__attribute__((address_space(3))) void*)l,
      16, 0, 0);
}

// ---------------------------------------------------------------------------
// prep: gather rows, compute row 1/||x||, write normalized bf16 (row-major)
// and raw bf16 transposed ET [DIM][NUM].
// grid (128, 2), block 256
// ---------------------------------------------------------------------------
__global__ __launch_bounds__(256) void prep_kernel(
    const float* __restrict__ e1, const float* __restrict__ e2,
    const int* __restrict__ idx1, const int* __restrict__ idx2,
    unsigned short* __restrict__ En1, unsigned short* __restrict__ En2,
    unsigned short* __restrict__ ET1, unsigned short* __restrict__ ET2) {
  __shared__ float tile[64][260];  // 260: keeps float4 16B alignment per row
  __shared__ float rinv[64];
  const int t = threadIdx.x;
  const int mat = blockIdx.y;
  const float* E = mat ? e2 : e1;
  const int* idx = mat ? idx2 : idx1;
  unsigned short* En = mat ? En2 : En1;
  unsigned short* ET = mat ? ET2 : ET1;
  const int r0 = blockIdx.x * 64;

  // load 64 gathered rows x 256 cols (fp32, coalesced float4)
#pragma unroll
  for (int p = 0; p < 16; ++p) {
    int flat = p * 256 + t;   // float4 id, 4096 total = 64 rows * 64
    int row = flat >> 6;
    int c4 = flat & 63;
    int src = idx[r0 + row];
    float4 v = *(const float4*)(E + (size_t)src * DIM + c4 * 4);
    *(float4*)(&tile[row][c4 * 4]) = v;
  }
  __syncthreads();

  // row energies: 4 threads per row, 64 floats each, combine via shfl
  {
    int row = t >> 2, part = t & 3;
    float s = 0.f;
#pragma unroll
    for (int q = 0; q < 64; ++q) {
      float x = tile[row][part * 64 + q];
      s += x * x;
    }
    s += __shfl_xor(s, 1, 64);
    s += __shfl_xor(s, 2, 64);
    if (part == 0) rinv[row] = rsqrtf(s);
  }
  __syncthreads();

  // write normalized bf16, row-major
#pragma unroll
  for (int p = 0; p < 16; ++p) {
    int flat = p * 256 + t;
    int row = flat >> 6;
    int c4 = flat & 63;
    float ri = rinv[row];
    float a = tile[row][c4 * 4 + 0] * ri;
    float b = tile[row][c4 * 4 + 1] * ri;
    float c = tile[row][c4 * 4 + 2] * ri;
    float d = tile[row][c4 * 4 + 3] * ri;
    uint2 o;
    o.x = (unsigned int)f2bf(a) | ((unsigned int)f2bf(b) << 16);
    o.y = (unsigned int)f2bf(c) | ((unsigned int)f2bf(d) << 16);
    *(uint2*)(En + (size_t)(r0 + row) * DIM + c4 * 4) = o;
  }

  // write raw bf16 transposed: ET[c][r0..r0+64]
  // group g (32 lanes) writes 32 cols; lane j writes dword j (rows 2j,2j+1)
  {
    int g = t >> 5;
    int j = t & 31;
#pragma unroll
    for (int cc = 0; cc < 32; ++cc) {
      int c = g * 32 + cc;
      unsigned int lo = f2bf(tile[2 * j][c]);
      unsigned int hi = f2bf(tile[2 * j + 1][c]);
      *(unsigned int*)(ET + (size_t)c * NUM + r0 + 2 * j) = lo | (hi << 16);
    }
  }
}

// ---------------------------------------------------------------------------
// gram: partial G = ET(128 rows) @ ET(128 rows)^T over a 512-wide K chunk.
// grid (4 quadrants, 16 k-chunks, 2 mats), block 256 (4 waves, 64x64 each)
// ---------------------------------------------------------------------------
__global__ __launch_bounds__(256) void gram_kernel(
    const unsigned short* __restrict__ ET1,
    const unsigned short* __restrict__ ET2,
    float* __restrict__ partials) {
  __shared__ unsigned short As[128 * 64];
  __shared__ unsigned short Bs[128 * 64];
  const int t = threadIdx.x;
  const int quadrant = blockIdx.x;
  const int kc = blockIdx.y;
  const int mat = blockIdx.z;
  const unsigned short* ET = mat ? ET2 : ET1;
  const int qi = quadrant >> 1, qj = quadrant & 1;
  const int wave = t >> 6, lane = t & 63;
  const int quad = lane >> 4, l15 = lane & 15;
  const int wr = (wave >> 1) * 64, wc = (wave & 1) * 64;

  f32x4 acc[4][4];
#pragma unroll
  for (int i = 0; i < 4; ++i)
#pragma unroll
    for (int j = 0; j < 4; ++j) {
      acc[i][j].x = 0.f; acc[i][j].y = 0.f; acc[i][j].z = 0.f; acc[i][j].w = 0.f;
    }

  const unsigned short* gA = ET + (size_t)(qi * 128) * NUM + kc * 512;
  const unsigned short* gB = ET + (size_t)(qj * 128) * NUM + kc * 512;

  for (int kk = 0; kk < 8; ++kk) {
#pragma unroll
    for (int p = 0; p < 4; ++p) {
      int flat = p * 256 + t;
      int row = flat >> 3, seg = flat & 7;
      async_copy16(gA + (size_t)row * NUM + kk * 64 + seg * 8,
                   As + row * 64 + seg * 8);
    }
#pragma unroll
    for (int p = 0; p < 4; ++p) {
      int flat = p * 256 + t;
      int row = flat >> 3, seg = flat & 7;
      async_copy16(gB + (size_t)row * NUM + kk * 64 + seg * 8,
                   Bs + row * 64 + seg * 8);
    }
    asm volatile("s_waitcnt vmcnt(0)" ::: "memory");
    __syncthreads();
#pragma unroll
    for (int ks = 0; ks < 2; ++ks) {
      bf16x8 aF[4], bF[4];
#pragma unroll
      for (int i = 0; i < 4; ++i)
        aF[i] = *(const bf16x8*)(As + (wr + i * 16 + l15) * 64 + ks * 32 + quad * 8);
#pragma unroll
      for (int j = 0; j < 4; ++j)
        bF[j] = *(const bf16x8*)(Bs + (wc + j * 16 + l15) * 64 + ks * 32 + quad * 8);
#pragma unroll
      for (int i = 0; i < 4; ++i)
#pragma unroll
        for (int j = 0; j < 4; ++j)
          acc[i][j] = __builtin_amdgcn_mfma_f32_16x16x32_bf16(aF[i], bF[j], acc[i][j], 0, 0, 0);
    }
    __syncthreads();
  }

  float* pw = partials + ((size_t)((mat * 4 + quadrant) * 16 + kc)) * 16384;
#pragma unroll
  for (int i = 0; i < 4; ++i)
#pragma unroll
    for (int r = 0; r < 4; ++r) {
      int rl = wr + i * 16 + quad * 4 + r;
#pragma unroll
      for (int j = 0; j < 4; ++j) {
        int cl = wc + j * 16 + l15;
        float v = (r == 0) ? acc[i][j].x : (r == 1) ? acc[i][j].y : (r == 2) ? acc[i][j].z : acc[i][j].w;
        pw[rl * 128 + cl] = v;
      }
    }
}

// ---------------------------------------------------------------------------
// gram reduce: sum k-chunk partials, subtract I, square, reduce -> d_out[1]
// grid 512, block 256 (one thread per (mat, quadrant, element))
// ---------------------------------------------------------------------------
__global__ __launch_bounds__(256) void gram_reduce_kernel(
    const float* __restrict__ partials, float* __restrict__ d_out) {
  int e = blockIdx.x * 256 + threadIdx.x;  // 0..131071
  int mat = e >> 16;
  int rem = e & 65535;
  int quadrant = rem >> 14;
  int li = rem & 16383;
  const float* p = partials + ((size_t)(mat * 4 + quadrant) * 16) * 16384 + li;
  float g = 0.f;
#pragma unroll
  for (int kc = 0; kc < 16; ++kc) g += p[(size_t)kc * 16384];
  int rl = li >> 7, cl = li & 127;
  int gr = (quadrant >> 1) * 128 + rl;
  int gc = (quadrant & 1) * 128 + cl;
  if (gr == gc) g -= 1.f;
  float s = g * g;
#pragma unroll
  for (int off = 32; off > 0; off >>= 1) s += __shfl_down(s, off, 64);
  __shared__ float wsum[4];
  int wave = threadIdx.x >> 6, lane = threadIdx.x & 63;
  if (lane == 0) wsum[wave] = s;
  __syncthreads();
  if (threadIdx.x == 0) atomicAdd(d_out + 1, wsum[0] + wsum[1] + wsum[2] + wsum[3]);
}

// ---------------------------------------------------------------------------
// main: 128x128 C-tile of cos = En1 @ En2^T, fused cost*trans reduction.
// grid (64, 64), block 256 (4 waves, each 64x64 = 4x4 frags of 16x16)
// ---------------------------------------------------------------------------
__global__ __launch_bounds__(256) void gw_main_kernel(
    const unsigned short* __restrict__ En1,
    const unsigned short* __restrict__ En2,
    const float* __restrict__ trans,
    float* __restrict__ d_out) {
  __shared__ unsigned short As[128 * 64];
  __shared__ unsigned short Bs[128 * 64];
  const int t = threadIdx.x;
  const int bx = blockIdx.x;  // col tile (En2)
  const int by = blockIdx.y;  // row tile (En1)
  const int wave = t >> 6, lane = t & 63;
  const int quad = lane >> 4, l15 = lane & 15;
  const int wr = (wave >> 1) * 64, wc = (wave & 1) * 64;

  f32x4 acc[4][4];
#pragma unroll
  for (int i = 0; i < 4; ++i)
#pragma unroll
    for (int j = 0; j < 4; ++j) {
      acc[i][j].x = 0.f; acc[i][j].y = 0.f; acc[i][j].z = 0.f; acc[i][j].w = 0.f;
    }

  const unsigned short* gA = En1 + (size_t)(by * 128) * DIM;
  const unsigned short* gB = En2 + (size_t)(bx * 128) * DIM;

  for (int kk = 0; kk < 4; ++kk) {  // K = 256, BK = 64
#pragma unroll
    for (int p = 0; p < 4; ++p) {
      int flat = p * 256 + t;  // 16B chunk id, 1024 per operand
      int row = flat >> 3, seg = flat & 7;
      async_copy16(gA + (size_t)row * DIM + kk * 64 + seg * 8,
                   As + row * 64 + seg * 8);
    }
#pragma unroll
    for (int p = 0; p < 4; ++p) {
      int flat = p * 256 + t;
      int row = flat >> 3, seg = flat & 7;
      async_copy16(gB + (size_t)row * DIM + kk * 64 + seg * 8,
                   Bs + row * 64 + seg * 8);
    }
    asm volatile("s_waitcnt vmcnt(0)" ::: "memory");
    __syncthreads();
#pragma unroll
    for (int ks = 0; ks < 2; ++ks) {
      bf16x8 aF[4], bF[4];
#pragma unroll
      for (int i = 0; i < 4; ++i)
        aF[i] = *(const bf16x8*)(As + (wr + i * 16 + l15) * 64 + ks * 32 + quad * 8);
#pragma unroll
      for (int j = 0; j < 4; ++j)
        bF[j] = *(const bf16x8*)(Bs + (wc + j * 16 + l15) * 64 + ks * 32 + quad * 8);
#pragma unroll
      for (int i = 0; i < 4; ++i)
#pragma unroll
        for (int j = 0; j < 4; ++j)
          acc[i][j] = __builtin_amdgcn_mfma_f32_16x16x32_bf16(aF[i], bF[j], acc[i][j], 0, 0, 0);
    }
    __syncthreads();
  }

  // epilogue: cost = 1 - exp(cos - 1); sum += trans * cost
  float sum = 0.f;
  const size_t row0 = (size_t)by * 128;
  const size_t col0 = (size_t)bx * 128;
#pragma unroll
  for (int i = 0; i < 4; ++i) {
#pragma unroll
    for (int r = 0; r < 4; ++r) {
      size_t grow = row0 + (size_t)(wr + i * 16 + quad * 4 + r);
      const float* trow = trans + grow * NUM + col0;
#pragma unroll
      for (int j = 0; j < 4; ++j) {
        float cosv = (r == 0) ? acc[i][j].x : (r == 1) ? acc[i][j].y : (r == 2) ? acc[i][j].z : acc[i][j].w;
        float cost = 1.f - __expf(cosv - 1.f);
        float w = trow[wc + j * 16 + l15];
        sum += w * cost;
      }
    }
  }
#pragma unroll
  for (int off = 32; off > 0; off >>= 1) sum += __shfl_down(sum, off, 64);
  __shared__ float wsum[4];
  if (lane == 0) wsum[wave] = sum;
  __syncthreads();
  if (t == 0) atomicAdd(d_out, wsum[0] + wsum[1] + wsum[2] + wsum[3]);
}

// ---------------------------------------------------------------------------
extern "C" void kernel_launch(void* const* d_in, const int* in_sizes, int n_in,
                              void* d_out, int out_size, void* d_ws, size_t ws_size,
                              hipStream_t stream) {
  const int* idx1 = (const int*)d_in[0];
  const int* idx2 = (const int*)d_in[1];
  const float* trans = (const float*)d_in[2];
  const float* e1 = (const float*)d_in[3];
  const float* e2 = (const float*)d_in[4];
  float* out = (float*)d_out;

  char* ws = (char*)d_ws;
  unsigned short* En1 = (unsigned short*)(ws);                    // 4 MB
  unsigned short* En2 = (unsigned short*)(ws + (4u << 20));       // 4 MB
  unsigned short* ET1 = (unsigned short*)(ws + (8u << 20));       // 4 MB
  unsigned short* ET2 = (unsigned short*)(ws + (12u << 20));      // 4 MB
  float* partials = (float*)(ws + (16u << 20));                   // 8 MB

  hipMemsetAsync(d_out, 0, 2 * sizeof(float), stream);
  hipLaunchKernelGGL(prep_kernel, dim3(128, 2), dim3(256), 0, stream,
                     e1, e2, idx1, idx2, En1, En2, ET1, ET2);
  hipLaunchKernelGGL(gram_kernel, dim3(4, 16, 2), dim3(256), 0, stream,
                     ET1, ET2, partials);
  hipLaunchKernelGGL(gram_reduce_kernel, dim3(512), dim3(256), 0, stream,
                     partials, out);
  hipLaunchKernelGGL(gw_main_kernel, dim3(64, 64), dim3(256), 0, stream,
                     En1, En2, trans, out);
}

// Round 2
// 424.338 us; speedup vs baseline: 1.2053x; 1.2053x over previous
//
#include <hip/hip_runtime.h>
#include <hip/hip_bf16.h>

#define NUM 8192
#define DIM 256

typedef __bf16 bf16x8 __attribute__((ext_vector_type(8)));
typedef float f32x4 __attribute__((ext_vector_type(4)));

// float -> bf16 round-to-nearest-even
__device__ __forceinline__ unsigned short f2bf(float x) {
  unsigned int u = __float_as_uint(x);
  unsigned int r = (u + 0x7FFFu + ((u >> 16) & 1u)) >> 16;
  return (unsigned short)r;
}

// async global->LDS, 16B per lane. LDS dest must be wave-uniform base + lane*16.
__device__ __forceinline__ void async_copy16(const void* g, void* l) {
  __builtin_amdgcn_global_load_lds(
      (const __attribute__((address_space(1))) void*)g,
      (__attribute__((address_space(3))) void*)l,
      16, 0, 0);
}

// ---------------------------------------------------------------------------
// prep: gather rows, compute row 1/||x||, write normalized bf16 (row-major)
// and raw bf16 transposed ET [DIM][NUM].
// grid (128, 2), block 256
// ---------------------------------------------------------------------------
__global__ __launch_bounds__(256) void prep_kernel(
    const float* __restrict__ e1, const float* __restrict__ e2,
    const int* __restrict__ idx1, const int* __restrict__ idx2,
    unsigned short* __restrict__ En1, unsigned short* __restrict__ En2,
    unsigned short* __restrict__ ET1, unsigned short* __restrict__ ET2) {
  __shared__ float tile[64][260];  // 260: keeps float4 16B alignment per row
  __shared__ float rinv[64];
  const int t = threadIdx.x;
  const int mat = blockIdx.y;
  const float* E = mat ? e2 : e1;
  const int* idx = mat ? idx2 : idx1;
  unsigned short* En = mat ? En2 : En1;
  unsigned short* ET = mat ? ET2 : ET1;
  const int r0 = blockIdx.x * 64;

  // load 64 gathered rows x 256 cols (fp32, coalesced float4)
#pragma unroll
  for (int p = 0; p < 16; ++p) {
    int flat = p * 256 + t;   // float4 id, 4096 total = 64 rows * 64
    int row = flat >> 6;
    int c4 = flat & 63;
    int src = idx[r0 + row];
    float4 v = *(const float4*)(E + (size_t)src * DIM + c4 * 4);
    *(float4*)(&tile[row][c4 * 4]) = v;
  }
  __syncthreads();

  // row energies: 4 threads per row; column-interleaved (stride 4) to spread
  // banks: bank = (4*row + 4*q + part) % 32 -> worst 2-way (free)
  {
    int row = t >> 2, part = t & 3;
    float s = 0.f;
#pragma unroll
    for (int q = 0; q < 64; ++q) {
      float x = tile[row][q * 4 + part];
      s += x * x;
    }
    s += __shfl_xor(s, 1, 64);
    s += __shfl_xor(s, 2, 64);
    if (part == 0) rinv[row] = rsqrtf(s);
  }
  __syncthreads();

  // write normalized bf16, row-major
#pragma unroll
  for (int p = 0; p < 16; ++p) {
    int flat = p * 256 + t;
    int row = flat >> 6;
    int c4 = flat & 63;
    float ri = rinv[row];
    float a = tile[row][c4 * 4 + 0] * ri;
    float b = tile[row][c4 * 4 + 1] * ri;
    float c = tile[row][c4 * 4 + 2] * ri;
    float d = tile[row][c4 * 4 + 3] * ri;
    uint2 o;
    o.x = (unsigned int)f2bf(a) | ((unsigned int)f2bf(b) << 16);
    o.y = (unsigned int)f2bf(c) | ((unsigned int)f2bf(d) << 16);
    *(uint2*)(En + (size_t)(r0 + row) * DIM + c4 * 4) = o;
  }

  // write raw bf16 transposed: ET[c][r0..r0+64]
  {
    int g = t >> 5;
    int j = t & 31;
#pragma unroll
    for (int cc = 0; cc < 32; ++cc) {
      int c = g * 32 + cc;
      unsigned int lo = f2bf(tile[2 * j][c]);
      unsigned int hi = f2bf(tile[2 * j + 1][c]);
      *(unsigned int*)(ET + (size_t)c * NUM + r0 + 2 * j) = lo | (hi << 16);
    }
  }
}

// ---------------------------------------------------------------------------
// gram: partial G = ET(128 rows) @ ET(128 rows)^T over a 512-wide K chunk.
// grid (4 quadrants, 16 k-chunks, 2 mats), block 256 (4 waves, 64x64 each)
// LDS XOR-swizzled: logical chunk c of row r stored at physical c^(r&7).
// ---------------------------------------------------------------------------
__global__ __launch_bounds__(256) void gram_kernel(
    const unsigned short* __restrict__ ET1,
    const unsigned short* __restrict__ ET2,
    float* __restrict__ partials) {
  __shared__ unsigned short As[128 * 64];
  __shared__ unsigned short Bs[128 * 64];
  const int t = threadIdx.x;
  const int quadrant = blockIdx.x;
  const int kc = blockIdx.y;
  const int mat = blockIdx.z;
  const unsigned short* ET = mat ? ET2 : ET1;
  const int qi = quadrant >> 1, qj = quadrant & 1;
  const int wave = t >> 6, lane = t & 63;
  const int quad = lane >> 4, l15 = lane & 15;
  const int wr = (wave >> 1) * 64, wc = (wave & 1) * 64;

  f32x4 acc[4][4];
#pragma unroll
  for (int i = 0; i < 4; ++i)
#pragma unroll
    for (int j = 0; j < 4; ++j) {
      acc[i][j].x = 0.f; acc[i][j].y = 0.f; acc[i][j].z = 0.f; acc[i][j].w = 0.f;
    }

  const unsigned short* gA = ET + (size_t)(qi * 128) * NUM + kc * 512;
  const unsigned short* gB = ET + (size_t)(qj * 128) * NUM + kc * 512;

  for (int kk = 0; kk < 8; ++kk) {
#pragma unroll
    for (int p = 0; p < 4; ++p) {
      int flat = p * 256 + t;
      int row = flat >> 3, seg = flat & 7;
      int segx = seg ^ (row & 7);  // permute global source -> swizzled LDS
      async_copy16(gA + (size_t)row * NUM + kk * 64 + segx * 8,
                   As + row * 64 + seg * 8);
    }
#pragma unroll
    for (int p = 0; p < 4; ++p) {
      int flat = p * 256 + t;
      int row = flat >> 3, seg = flat & 7;
      int segx = seg ^ (row & 7);
      async_copy16(gB + (size_t)row * NUM + kk * 64 + segx * 8,
                   Bs + row * 64 + seg * 8);
    }
    asm volatile("s_waitcnt vmcnt(0)" ::: "memory");
    __syncthreads();
#pragma unroll
    for (int ks = 0; ks < 2; ++ks) {
      bf16x8 aF[4], bF[4];
      const int swz = (ks * 4 + quad) ^ (l15 & 7);  // row&7 == l15&7 here
#pragma unroll
      for (int i = 0; i < 4; ++i)
        aF[i] = *(const bf16x8*)(As + (wr + i * 16 + l15) * 64 + swz * 8);
#pragma unroll
      for (int j = 0; j < 4; ++j)
        bF[j] = *(const bf16x8*)(Bs + (wc + j * 16 + l15) * 64 + swz * 8);
#pragma unroll
      for (int i = 0; i < 4; ++i)
#pragma unroll
        for (int j = 0; j < 4; ++j)
          acc[i][j] = __builtin_amdgcn_mfma_f32_16x16x32_bf16(aF[i], bF[j], acc[i][j], 0, 0, 0);
    }
    __syncthreads();
  }

  float* pw = partials + ((size_t)((mat * 4 + quadrant) * 16 + kc)) * 16384;
#pragma unroll
  for (int i = 0; i < 4; ++i)
#pragma unroll
    for (int r = 0; r < 4; ++r) {
      int rl = wr + i * 16 + quad * 4 + r;
#pragma unroll
      for (int j = 0; j < 4; ++j) {
        int cl = wc + j * 16 + l15;
        float v = (r == 0) ? acc[i][j].x : (r == 1) ? acc[i][j].y : (r == 2) ? acc[i][j].z : acc[i][j].w;
        pw[rl * 128 + cl] = v;
      }
    }
}

// ---------------------------------------------------------------------------
// gram reduce: sum k-chunk partials, subtract I, square, reduce -> d_out[1]
// ---------------------------------------------------------------------------
__global__ __launch_bounds__(256) void gram_reduce_kernel(
    const float* __restrict__ partials, float* __restrict__ d_out) {
  int e = blockIdx.x * 256 + threadIdx.x;  // 0..131071
  int mat = e >> 16;
  int rem = e & 65535;
  int quadrant = rem >> 14;
  int li = rem & 16383;
  const float* p = partials + ((size_t)(mat * 4 + quadrant) * 16) * 16384 + li;
  float g = 0.f;
#pragma unroll
  for (int kc = 0; kc < 16; ++kc) g += p[(size_t)kc * 16384];
  int rl = li >> 7, cl = li & 127;
  int gr = (quadrant >> 1) * 128 + rl;
  int gc = (quadrant & 1) * 128 + cl;
  if (gr == gc) g -= 1.f;
  float s = g * g;
#pragma unroll
  for (int off = 32; off > 0; off >>= 1) s += __shfl_down(s, off, 64);
  __shared__ float wsum[4];
  int wave = threadIdx.x >> 6, lane = threadIdx.x & 63;
  if (lane == 0) wsum[wave] = s;
  __syncthreads();
  if (threadIdx.x == 0) atomicAdd(d_out + 1, wsum[0] + wsum[1] + wsum[2] + wsum[3]);
}

// ---------------------------------------------------------------------------
// main: OPERAND-SWAPPED 128x128 tile: acc = cos^T (rows = En2 idx, cols = En1
// idx), so each fragment's 4 regs are 4 consecutive trans columns -> float4.
// grid (64 bx = En2 tiles, 64 by = En1 tiles), block 256.
// ---------------------------------------------------------------------------
__global__ __launch_bounds__(256) void gw_main_kernel(
    const unsigned short* __restrict__ En1,
    const unsigned short* __restrict__ En2,
    const float* __restrict__ trans,
    float* __restrict__ d_out) {
  __shared__ unsigned short As[128 * 64];  // En2 tile (M side)
  __shared__ unsigned short Bs[128 * 64];  // En1 tile (N side)
  const int t = threadIdx.x;
  const int bx = blockIdx.x;  // En2 tile
  const int by = blockIdx.y;  // En1 tile
  const int wave = t >> 6, lane = t & 63;
  const int quad = lane >> 4, l15 = lane & 15;
  const int wr = (wave >> 1) * 64, wc = (wave & 1) * 64;

  f32x4 acc[4][4];
#pragma unroll
  for (int i = 0; i < 4; ++i)
#pragma unroll
    for (int j = 0; j < 4; ++j) {
      acc[i][j].x = 0.f; acc[i][j].y = 0.f; acc[i][j].z = 0.f; acc[i][j].w = 0.f;
    }

  const unsigned short* gA = En2 + (size_t)(bx * 128) * DIM;
  const unsigned short* gB = En1 + (size_t)(by * 128) * DIM;

  for (int kk = 0; kk < 4; ++kk) {  // K = 256, BK = 64
#pragma unroll
    for (int p = 0; p < 4; ++p) {
      int flat = p * 256 + t;  // 16B chunk id, 1024 per operand
      int row = flat >> 3, seg = flat & 7;
      int segx = seg ^ (row & 7);  // XOR swizzle (global side permuted)
      async_copy16(gA + (size_t)row * DIM + kk * 64 + segx * 8,
                   As + row * 64 + seg * 8);
    }
#pragma unroll
    for (int p = 0; p < 4; ++p) {
      int flat = p * 256 + t;
      int row = flat >> 3, seg = flat & 7;
      int segx = seg ^ (row & 7);
      async_copy16(gB + (size_t)row * DIM + kk * 64 + segx * 8,
                   Bs + row * 64 + seg * 8);
    }
    asm volatile("s_waitcnt vmcnt(0)" ::: "memory");
    __syncthreads();
#pragma unroll
    for (int ks = 0; ks < 2; ++ks) {
      bf16x8 aF[4], bF[4];
      const int swz = (ks * 4 + quad) ^ (l15 & 7);
#pragma unroll
      for (int i = 0; i < 4; ++i)
        aF[i] = *(const bf16x8*)(As + (wr + i * 16 + l15) * 64 + swz * 8);
#pragma unroll
      for (int j = 0; j < 4; ++j)
        bF[j] = *(const bf16x8*)(Bs + (wc + j * 16 + l15) * 64 + swz * 8);
#pragma unroll
      for (int i = 0; i < 4; ++i)
#pragma unroll
        for (int j = 0; j < 4; ++j)
          acc[i][j] = __builtin_amdgcn_mfma_f32_16x16x32_bf16(aF[i], bF[j], acc[i][j], 0, 0, 0);
    }
    __syncthreads();
  }

  // epilogue: acc[i][j] reg r holds cos(En1[by*128+wc+j*16+l15],
  //                                    En2[bx*128+wr+i*16+quad*4+r])
  // trans element = trans[en1_idx][en2_idx]; regs r=0..3 are 4 consecutive
  // columns -> one float4 per fragment. Issue all 16 loads first.
  f32x4 tw[4][4];
#pragma unroll
  for (int i = 0; i < 4; ++i) {
#pragma unroll
    for (int j = 0; j < 4; ++j) {
      size_t r1 = (size_t)(by * 128 + wc + j * 16 + l15);
      size_t c2 = (size_t)(bx * 128 + wr + i * 16 + quad * 4);
      tw[i][j] = __builtin_nontemporal_load((const f32x4*)(trans + r1 * NUM + c2));
    }
  }
  float sum = 0.f;
#pragma unroll
  for (int i = 0; i < 4; ++i) {
#pragma unroll
    for (int j = 0; j < 4; ++j) {
      f32x4 c = acc[i][j];
      f32x4 w = tw[i][j];
      sum += w.x * (1.f - __expf(c.x - 1.f));
      sum += w.y * (1.f - __expf(c.y - 1.f));
      sum += w.z * (1.f - __expf(c.z - 1.f));
      sum += w.w * (1.f - __expf(c.w - 1.f));
    }
  }
#pragma unroll
  for (int off = 32; off > 0; off >>= 1) sum += __shfl_down(sum, off, 64);
  __shared__ float wsum[4];
  if (lane == 0) wsum[wave] = sum;
  __syncthreads();
  if (t == 0) atomicAdd(d_out, wsum[0] + wsum[1] + wsum[2] + wsum[3]);
}

// ---------------------------------------------------------------------------
extern "C" void kernel_launch(void* const* d_in, const int* in_sizes, int n_in,
                              void* d_out, int out_size, void* d_ws, size_t ws_size,
                              hipStream_t stream) {
  const int* idx1 = (const int*)d_in[0];
  const int* idx2 = (const int*)d_in[1];
  const float* trans = (const float*)d_in[2];
  const float* e1 = (const float*)d_in[3];
  const float* e2 = (const float*)d_in[4];
  float* out = (float*)d_out;

  char* ws = (char*)d_ws;
  unsigned short* En1 = (unsigned short*)(ws);                    // 4 MB
  unsigned short* En2 = (unsigned short*)(ws + (4u << 20));       // 4 MB
  unsigned short* ET1 = (unsigned short*)(ws + (8u << 20));       // 4 MB
  unsigned short* ET2 = (unsigned short*)(ws + (12u << 20));      // 4 MB
  float* partials = (float*)(ws + (16u << 20));                   // 8 MB

  hipMemsetAsync(d_out, 0, 2 * sizeof(float), stream);
  hipLaunchKernelGGL(prep_kernel, dim3(128, 2), dim3(256), 0, stream,
                     e1, e2, idx1, idx2, En1, En2, ET1, ET2);
  hipLaunchKernelGGL(gram_kernel, dim3(4, 16, 2), dim3(256), 0, stream,
                     ET1, ET2, partials);
  hipLaunchKernelGGL(gram_reduce_kernel, dim3(512), dim3(256), 0, stream,
                     partials, out);
  hipLaunchKernelGGL(gw_main_kernel, dim3(64, 64), dim3(256), 0, stream,
                     En1, En2, trans, out);
}